// Round 4
// baseline (8296.552 us; speedup 1.0000x reference)
//
#include <hip/hip_runtime.h>
#include <hip/hip_bf16.h>
#include <hip/hip_cooperative_groups.h>
#include <math.h>

namespace cg = cooperative_groups;

// Problem dims (fixed)
#define B   64
#define NN  196
#define HH  512
#define EE  512
#define AA  512
#define VV  20000
#define LL  20

typedef __attribute__((ext_vector_type(8))) short bf16x8;
typedef __attribute__((ext_vector_type(4))) float floatx4;

__device__ __forceinline__ float tanh_fast(float x) {
  float e2 = __expf(2.f * x);
  return 1.f - 2.f / (e2 + 1.f);
}
__device__ __forceinline__ float sigmoid_fast(float x) {
  return 1.f / (1.f + __expf(-x));
}
__device__ __forceinline__ float b2f(unsigned short u) {
  unsigned int v = ((unsigned int)u) << 16;
  float f;
  __builtin_memcpy(&f, &v, 4);
  return f;
}
__device__ __forceinline__ unsigned short f2b(float f) {
  __hip_bfloat16 h = __float2bfloat16(f);
  unsigned short u;
  __builtin_memcpy(&u, &h, 2);
  return u;
}

// ---------------------------------------------------------------------------
// bf16 MFMA GEMM: C[M,N] = Xb[M,K](bf16) @ Wb[N,K](bf16)^T + bias
// 128x128 tile, BK=32, 256 threads = 4 waves.
// outMode 0: C[m*ldC+n] fp32
// outMode 1: logits scatter out[b, t+1, n], m = t*64+b
// outMode 2: gt_pre layout C[((m>>6)*2048 + n)*64 + (m&63)], guard m<M
// outMode 3: bf16 output C16[m*ldC+n]
// ---------------------------------------------------------------------------
__global__ __launch_bounds__(256) void gemm_mfma_bt(
    const unsigned short* __restrict__ Xb, const unsigned short* __restrict__ Wb,
    const float* __restrict__ bias, float* __restrict__ C,
    unsigned short* __restrict__ C16, int M, int N, int K, int ldC, int outMode) {
  __shared__ unsigned short As[128 * 32];
  __shared__ unsigned short Bs[128 * 32];
  const int tid = threadIdx.x;
  const int lane = tid & 63;
  const int l15 = lane & 15;
  const int q = lane >> 4;
  const int wv = tid >> 6;
  const int wm = (wv >> 1) * 64;
  const int wn = (wv & 1) * 64;
  const int mBase = blockIdx.y * 128;
  const int nBase = blockIdx.x * 128;

  const int c0 = tid, c1 = tid + 256;
  const int r0 = c0 >> 2, o0 = (c0 & 3) * 8;
  const int r1 = c1 >> 2, o1 = (c1 & 3) * 8;

  floatx4 zero = {0.f, 0.f, 0.f, 0.f};
  floatx4 acc[4][4];
#pragma unroll
  for (int i = 0; i < 4; ++i)
#pragma unroll
    for (int j = 0; j < 4; ++j) acc[i][j] = zero;

  for (int k0 = 0; k0 < K; k0 += 32) {
    uint4 a0 = *(const uint4*)(Xb + (size_t)(mBase + r0) * K + k0 + o0);
    uint4 a1 = *(const uint4*)(Xb + (size_t)(mBase + r1) * K + k0 + o1);
    uint4 b0 = *(const uint4*)(Wb + (size_t)(nBase + r0) * K + k0 + o0);
    uint4 b1 = *(const uint4*)(Wb + (size_t)(nBase + r1) * K + k0 + o1);
    __syncthreads();
    *(uint4*)&As[c0 * 8] = a0;
    *(uint4*)&As[c1 * 8] = a1;
    *(uint4*)&Bs[c0 * 8] = b0;
    *(uint4*)&Bs[c1 * 8] = b1;
    __syncthreads();
    bf16x8 af[4], bfv[4];
#pragma unroll
    for (int i = 0; i < 4; ++i)
      af[i] = *(const bf16x8*)&As[(wm + i * 16 + l15) * 32 + q * 8];
#pragma unroll
    for (int j = 0; j < 4; ++j)
      bfv[j] = *(const bf16x8*)&Bs[(wn + j * 16 + l15) * 32 + q * 8];
#pragma unroll
    for (int i = 0; i < 4; ++i)
#pragma unroll
      for (int j = 0; j < 4; ++j)
        acc[i][j] = __builtin_amdgcn_mfma_f32_16x16x32_bf16(af[i], bfv[j],
                                                            acc[i][j], 0, 0, 0);
  }

#pragma unroll
  for (int i = 0; i < 4; ++i) {
#pragma unroll
    for (int j = 0; j < 4; ++j) {
#pragma unroll
      for (int p = 0; p < 4; ++p) {
        int m = mBase + wm + i * 16 + q * 4 + p;
        int n = nBase + wn + j * 16 + l15;
        if (m < M && n < N) {
          float v = acc[i][j][p];
          if (bias) v += bias[n];
          if (outMode == 1) {
            C[(size_t)(m & 63) * ((size_t)LL * VV) + (size_t)((m >> 6) + 1) * VV + n] = v;
          } else if (outMode == 2) {
            C[((size_t)(m >> 6) * 2048 + n) * 64 + (m & 63)] = v;
          } else if (outMode == 3) {
            C16[(size_t)m * ldC + n] = f2b(v);
          } else {
            C[(size_t)m * ldC + n] = v;
          }
        }
      }
    }
  }
}

// ---------------------------------------------------------------------------
// fp32 -> bf16 conversion with row padding and stride.
// ---------------------------------------------------------------------------
__global__ __launch_bounds__(256) void convert_pad(
    const float* __restrict__ src, unsigned short* __restrict__ dst,
    int srcRows, int dstRows, int srcStride, int colOff) {
  int idx = blockIdx.x * 256 + threadIdx.x;
  if (idx >= dstRows * 512) return;
  int r = idx >> 9, cc = idx & 511;
  float v = (r < srcRows) ? src[(size_t)r * srcStride + colOff + cc] : 0.f;
  dst[idx] = f2b(v);
}

// ---------------------------------------------------------------------------
// Pack weights: Wb3[2048][1024] = [W_hh | W_ih[:,512:1024]], bsum = b_ih+b_hh
// ---------------------------------------------------------------------------
__global__ __launch_bounds__(256) void build_weights(
    const float* __restrict__ W_ih, const float* __restrict__ W_hh,
    const float* __restrict__ b_ih, const float* __restrict__ b_hh,
    float* __restrict__ Wb3, float* __restrict__ bsum) {
  int idx = blockIdx.x * 256 + threadIdx.x;
  if (idx < 2048 * 1024) {
    int n = idx >> 10, k = idx & 1023;
    Wb3[idx] = (k < 512) ? W_hh[(size_t)n * 512 + k]
                         : W_ih[(size_t)n * 1024 + 512 + (k - 512)];
  }
  if (idx < 2048) bsum[idx] = b_ih[idx] + b_hh[idx];
}

// ---------------------------------------------------------------------------
// Gather embeddings -> bf16, rows m = t*64+b, zero pad rows 1216..1279
// ---------------------------------------------------------------------------
__global__ __launch_bounds__(256) void gather_emb(
    const float* __restrict__ emb, const int* __restrict__ captions,
    unsigned short* __restrict__ embx) {
  int m = blockIdx.x;
  int tid = threadIdx.x;
  if (m >= 1216) {
    embx[(size_t)m * 512 + tid] = 0;
    embx[(size_t)m * 512 + 256 + tid] = 0;
    return;
  }
  int t = m >> 6, b = m & 63;
  int cap = captions[b * LL + t];
#pragma unroll
  for (int i = 0; i < 2; ++i)
    embx[(size_t)m * 512 + i * 256 + tid] = f2b(emb[(size_t)cap * 512 + i * 256 + tid]);
}

__global__ __launch_bounds__(256) void zero_t0_kernel(float* __restrict__ out) {
  int idx = blockIdx.x * 256 + threadIdx.x;
  if (idx < B * VV) {
    int b = idx / VV, v = idx % VV;
    out[(size_t)b * ((size_t)LL * VV) + v] = 0.f;
  }
}

// ---------------------------------------------------------------------------
// Persistent cooperative kernel: all 19 recurrent steps.
// Grid = 256 blocks x 512 threads. Phases per step (grid.sync between):
//  P1: dec[b][j]  (block: 2 j-cols x all b; ht k-major coalesced)
//  P2a: scores    (block: (b, n-quarter); enc_proj bf16)
//  P2b: softmax + context (block: (b, h-slice-of-128); enc_out bf16)
//  P3: gates GEMM (x=[h|ctx] bf16-staged LDS, W fp32 uniform float4 loads)
//      fused with LSTM pointwise -> ct, ht, h, hb(bf16)
// ---------------------------------------------------------------------------
__global__ __launch_bounds__(512) void decoder_loop(
    const unsigned short* __restrict__ eo16,   // enc_out bf16 [64*196][512]
    const unsigned short* __restrict__ ep16,   // enc_proj bf16 [64*196][512]
    const float* __restrict__ dec_W, const float* __restrict__ dec_b,
    const float* __restrict__ eW, const float* __restrict__ eb,
    const float* __restrict__ Wb3,             // [2048][1024] fp32
    const float* __restrict__ gt_pre,          // [19][2048][64] fp32
    float* __restrict__ ht,                    // [512][64]
    float* __restrict__ h,                     // [64][512]
    float* __restrict__ dec,                   // [64][512]
    float* __restrict__ scores,                // [64][196]
    float* __restrict__ ctx,                   // [64][512]
    float* __restrict__ ct,                    // [512][64]
    unsigned short* __restrict__ hb) {         // [1280][512] bf16
  cg::grid_group grid = cg::this_grid();
  __shared__ float smem[9856];
  const int tid = threadIdx.x;
  const int bid = blockIdx.x;
  const int lane = tid & 63;
  const int wv = tid >> 6;

  char* xs = (char*)(smem + 1024);        // bf16 x-stage [64][260] = 33280 B
  float* gl = smem + 1024;                // alias (used after FMA done)
  float* gl2 = smem + 9344;               // [8][64]

  for (int t = 0; t < 19; ++t) {
    // ---------------- P1: dec ----------------
    {
      const int jsub = wv & 1, ks = wv >> 1;
      const int j = bid * 2 + jsub;
      const float* wrow = dec_W + (size_t)j * 512 + ks * 128;
      const float* hcol = ht + ks * 128 * 64 + lane;
      float acc = 0.f;
#pragma unroll 8
      for (int kk = 0; kk < 128; ++kk) acc += hcol[kk * 64] * wrow[kk];
      smem[wv * 64 + lane] = acc;
      __syncthreads();
      if (wv < 2) {
        float s = smem[wv * 64 + lane] + smem[(2 + wv) * 64 + lane] +
                  smem[(4 + wv) * 64 + lane] + smem[(6 + wv) * 64 + lane];
        dec[lane * 512 + bid * 2 + wv] = s + dec_b[bid * 2 + wv];
      }
    }
    grid.sync();
    // ---------------- P2a: scores ----------------
    {
      const int b = bid >> 2, q = bid & 3;
      smem[tid] = dec[b * 512 + tid];
      __syncthreads();
      float ew[8], sd[8];
#pragma unroll
      for (int j = 0; j < 8; ++j) {
        ew[j] = eW[j * 64 + lane];
        sd[j] = smem[j * 64 + lane];
      }
      for (int idx = wv; idx < 49; idx += 8) {
        int n = q * 49 + idx;
        const unsigned short* ep = ep16 + ((size_t)b * NN + n) * 512;
        float a = 0.f;
#pragma unroll
        for (int j = 0; j < 8; ++j)
          a += tanh_fast(b2f(ep[j * 64 + lane]) + sd[j]) * ew[j];
#pragma unroll
        for (int off = 32; off; off >>= 1) a += __shfl_down(a, off, 64);
        if (lane == 0) scores[b * NN + n] = a + eb[0];
      }
    }
    grid.sync();
    // ---------------- P2b: softmax + context ----------------
    {
      const int b = bid >> 2, q = bid & 3;
      float* sw = smem;         // [0..195]
      float* tmp = smem + 256;  // [256..511]
      float v = (tid < NN) ? scores[b * NN + tid] : -1e30f;
      if (tid < 256) tmp[tid] = v;
      __syncthreads();
      for (int s = 128; s; s >>= 1) {
        if (tid < s) tmp[tid] = fmaxf(tmp[tid], tmp[tid + s]);
        __syncthreads();
      }
      float mx = tmp[0];
      __syncthreads();
      float e = (tid < NN) ? __expf(v - mx) : 0.f;
      if (tid < 256) tmp[tid] = e;
      __syncthreads();
      for (int s = 128; s; s >>= 1) {
        if (tid < s) tmp[tid] += tmp[tid + s];
        __syncthreads();
      }
      float inv = 1.f / tmp[0];
      __syncthreads();
      if (tid < NN) sw[tid] = e * inv;
      __syncthreads();
      // context: thread (h' = tid&127, ng = tid>>7); h-slice q*128..+128
      const int hp = tid & 127, ng = tid >> 7;
      float acc = 0.f;
      const unsigned short* eo = eo16 + (size_t)b * NN * 512 + q * 128 + hp;
      for (int i = 0; i < 49; ++i) {
        int n = ng * 49 + i;
        acc += sw[n] * b2f(eo[(size_t)n * 512]);
      }
      smem[512 + ng * 128 + hp] = acc;
      __syncthreads();
      if (tid < 128) {
        float s = smem[512 + tid] + smem[640 + tid] + smem[768 + tid] + smem[896 + tid];
        ctx[b * 512 + q * 128 + tid] = s;
      }
    }
    grid.sync();
    // ---------------- P3: gates + pointwise ----------------
    {
      const int j0 = bid * 2;
      float acc8[8];
#pragma unroll
      for (int i = 0; i < 8; ++i) acc8[i] = 0.f;

      for (int p = 0; p < 4; ++p) {
        const int kbase = p * 256;
        __syncthreads();
        // stage x chunk [64 b][256 k] as bf16 into xs (row stride 520 B)
#pragma unroll
        for (int s = 0; s < 8; ++s) {
          int idx = tid + s * 512;
          int b = idx >> 6, kq = idx & 63;
          int k = kbase + kq * 4;
          float4 v;
          if (k < 512) v = *(const float4*)(h + (size_t)b * 512 + k);
          else         v = *(const float4*)(ctx + (size_t)b * 512 + (k - 512));
          uint2 pk;
          pk.x = (unsigned int)f2b(v.x) | ((unsigned int)f2b(v.y) << 16);
          pk.y = (unsigned int)f2b(v.z) | ((unsigned int)f2b(v.w) << 16);
          *(uint2*)(xs + b * 520 + kq * 8) = pk;
        }
        __syncthreads();
        // FMA: wave wv covers local k in [wv*32, wv*32+32), 8 n outputs
        for (int kq = 0; kq < 8; ++kq) {
          int kl = wv * 32 + kq * 4;
          int kg = kbase + kl;
          float4 w4[8];
#pragma unroll
          for (int np = 0; np < 8; ++np) {
            int n = (np >> 1) * 512 + j0 + (np & 1);
            w4[np] = *(const float4*)(Wb3 + (size_t)n * 1024 + kg);
          }
          uint2 xv = *(const uint2*)(xs + lane * 520 + kl * 2);
          float x0 = b2f((unsigned short)(xv.x & 0xffff));
          float x1 = b2f((unsigned short)(xv.x >> 16));
          float x2 = b2f((unsigned short)(xv.y & 0xffff));
          float x3 = b2f((unsigned short)(xv.y >> 16));
#pragma unroll
          for (int np = 0; np < 8; ++np)
            acc8[np] += x0 * w4[np].x + x1 * w4[np].y + x2 * w4[np].z + x3 * w4[np].w;
        }
      }
      __syncthreads();  // all FMA done before gl overwrites xs
#pragma unroll
      for (int np = 0; np < 8; ++np) gl[(wv * 8 + np) * 64 + lane] = acc8[np];
      __syncthreads();
      // reduce 8 wave-partials; add gt_pre
      {
        int n2 = tid >> 6;  // 0..7
        float g = 0.f;
#pragma unroll
        for (int w2 = 0; w2 < 8; ++w2) g += gl[(w2 * 8 + n2) * 64 + lane];
        int n = (n2 >> 1) * 512 + j0 + (n2 & 1);
        g += gt_pre[((size_t)t * 2048 + n) * 64 + lane];
        gl2[n2 * 64 + lane] = g;
      }
      __syncthreads();
      // pointwise (tid < 128): jsub = tid>>6, b = lane
      if (tid < 128) {
        int jsub = tid >> 6, b = lane;
        int j = j0 + jsub;
        float iv = gl2[(0 * 2 + jsub) * 64 + b];
        float fv = gl2[(1 * 2 + jsub) * 64 + b];
        float gv = gl2[(2 * 2 + jsub) * 64 + b];
        float ov = gl2[(3 * 2 + jsub) * 64 + b];
        float c_old = ct[j * 64 + b];
        float cn = sigmoid_fast(fv) * c_old + sigmoid_fast(iv) * tanh_fast(gv);
        float hn = sigmoid_fast(ov) * tanh_fast(cn);
        ct[j * 64 + b] = cn;
        ht[j * 64 + b] = hn;
        h[(size_t)b * 512 + j] = hn;
        hb[((size_t)(t * 64 + b)) * 512 + j] = f2b(hn);
      }
    }
    grid.sync();
  }
}

extern "C" void kernel_launch(void* const* d_in, const int* in_sizes, int n_in,
                              void* d_out, int out_size, void* d_ws, size_t ws_size,
                              hipStream_t stream) {
  const float* enc_out  = (const float*)d_in[0];
  const int*   captions = (const int*)d_in[1];
  const float* emb      = (const float*)d_in[2];
  const float* W_ih     = (const float*)d_in[3];
  const float* W_hh     = (const float*)d_in[4];
  const float* b_ih     = (const float*)d_in[5];
  const float* b_hh     = (const float*)d_in[6];
  const float* enc_W    = (const float*)d_in[7];
  const float* enc_b    = (const float*)d_in[8];
  const float* dec_W    = (const float*)d_in[9];
  const float* dec_b    = (const float*)d_in[10];
  const float* energy_W = (const float*)d_in[11];
  const float* energy_b = (const float*)d_in[12];
  const float* fc_W     = (const float*)d_in[13];
  const float* fc_b     = (const float*)d_in[14];
  float* out = (float*)d_out;

  // Workspace layout (floats first, then bf16)
  float* ws = (float*)d_ws;
  float* Wb3    = ws;                          // 2048*1024
  float* gt_pre = Wb3 + (size_t)2048 * 1024;   // 19*2048*64
  float* bsum   = gt_pre + (size_t)19 * 2048 * 64; // 2048
  float* ht     = bsum + 2048;                 // 32768
  float* h      = ht + 32768;                  // 32768
  float* ct     = h + 32768;                   // 32768
  float* dec    = ct + 32768;                  // 32768
  float* scores = dec + 32768;                 // 12544
  float* ctx    = scores + 12544;              // 32768
  unsigned short* fcWb  = (unsigned short*)(ctx + 32768);      // 20096*512
  unsigned short* encWb = fcWb + (size_t)20096 * 512;          // 512*512
  unsigned short* eo16  = encWb + (size_t)512 * 512;           // 12544*512
  unsigned short* Wb0b  = eo16 + (size_t)12544 * 512;          // 2048*512
  unsigned short* embx  = Wb0b + (size_t)2048 * 512;           // 1280*512
  unsigned short* ep16  = embx + (size_t)1280 * 512;           // 12544*512
  unsigned short* hb    = ep16 + (size_t)12544 * 512;          // 1280*512

  hipMemsetAsync(ht, 0, 32768 * sizeof(float), stream);
  hipMemsetAsync(h, 0, 32768 * sizeof(float), stream);
  hipMemsetAsync(ct, 0, 32768 * sizeof(float), stream);
  hipMemsetAsync(hb, 0, (size_t)1280 * 512 * sizeof(unsigned short), stream);
  zero_t0_kernel<<<(B * VV + 255) / 256, 256, 0, stream>>>(out);

  build_weights<<<(2048 * 1024) / 256, 256, 0, stream>>>(W_ih, W_hh, b_ih, b_hh,
                                                         Wb3, bsum);
  convert_pad<<<(20096 * 512) / 256, 256, 0, stream>>>(fc_W, fcWb, 20000, 20096, 512, 0);
  convert_pad<<<(512 * 512) / 256, 256, 0, stream>>>(enc_W, encWb, 512, 512, 512, 0);
  convert_pad<<<(12544 * 512) / 256, 256, 0, stream>>>(enc_out, eo16, 12544, 12544, 512, 0);
  convert_pad<<<(2048 * 512) / 256, 256, 0, stream>>>(W_ih, Wb0b, 2048, 2048, 1024, 0);
  gather_emb<<<1280, 256, 0, stream>>>(emb, captions, embx);

  // gt_pre[t][n][b] = (embx @ W_ih_emb^T + b_ih + b_hh)
  gemm_mfma_bt<<<dim3(16, 10), 256, 0, stream>>>(
      embx, Wb0b, bsum, gt_pre, nullptr, 1216, 2048, 512, 2048, 2);

  // enc_proj (bf16) = enc_out @ enc_W^T + enc_b
  gemm_mfma_bt<<<dim3(4, 98), 256, 0, stream>>>(
      eo16, encWb, enc_b, nullptr, ep16, 12544, 512, 512, 512, 3);

  // Persistent cooperative recurrent loop (19 steps)
  {
    const unsigned short* a_eo16 = eo16;
    const unsigned short* a_ep16 = ep16;
    void* kp[] = {
        (void*)&a_eo16, (void*)&a_ep16, (void*)&dec_W, (void*)&dec_b,
        (void*)&energy_W, (void*)&energy_b, (void*)&Wb3, (void*)&gt_pre,
        (void*)&ht, (void*)&h, (void*)&dec, (void*)&scores, (void*)&ctx,
        (void*)&ct, (void*)&hb};
    hipLaunchCooperativeKernel((void*)decoder_loop, dim3(256), dim3(512), kp, 0,
                               stream);
  }

  // Batched logits: out[b, t+1, :] = h_{t+1} @ fc_W^T + fc_b
  gemm_mfma_bt<<<dim3(157, 10), 256, 0, stream>>>(
      hb, fcWb, fc_b, out, nullptr, 1216, 20000, 512, 0, 1);
}